// Round 1
// baseline (273.678 us; speedup 1.0000x reference)
//
#include <hip/hip_runtime.h>

#define TRAJ_LEN 2048
#define BLOCK 256

__global__ __launch_bounds__(BLOCK) void sig_kernel(const float* __restrict__ traj,
                                                    float* __restrict__ out) {
    const int b = blockIdx.x;
    const float* base = traj + (size_t)b * TRAJ_LEN * 6;

    // per-thread accumulators
    float curv = 0.f, cnt = 0.f;     // path curvature sum, mask count
    float dvel = 0.f, jerk = 0.f;    // sum |dvel| components, sum |dacc| components
    float ssum = 0.f, ssq = 0.f;     // speed sum, speed^2 sum
    float fsum = 0.f, fsq = 0.f;     // force sum, force^2 sum

    for (int r = threadIdx.x; r < TRAJ_LEN; r += BLOCK) {
        const float* row = base + r * 6;
        // row layout: [px, py, vx, vy, ax, ay]
        float px = row[0], py = row[1];
        float vx = row[2], vy = row[3];
        float ax = row[4], ay = row[5];

        float sp = sqrtf(vx * vx + vy * vy);
        ssum += sp;  ssq += sp * sp;
        float fo = sqrtf(ax * ax + ay * ay);
        fsum += fo;  fsq += fo * fo;

        if (r >= 1) {
            const float* prow = row - 6;   // previous row: loaded by adjacent lane too -> L1 hit
            float pvx = prow[2], pvy = prow[3];
            float pax = prow[4], pay = prow[5];
            dvel += fabsf(vx - pvx) + fabsf(vy - pvy);
            jerk += fabsf(ax - pax) + fabsf(ay - pay);
            if (r >= 2) {
                // v1 = traj[r-1,:2], v2 = traj[r,:2]  (cumsum differences telescope)
                float ppx = prow[0], ppy = prow[1];
                float cross = ppx * py - ppy * px;
                float n = sqrtf(ppx * ppx + ppy * ppy) * sqrtf(px * px + py * py);
                if (n > 1e-6f) {
                    curv += fabsf(cross) / n;
                    cnt += 1.f;
                }
            }
        }
    }

    // wave-level butterfly reduce (64 lanes)
#pragma unroll
    for (int off = 32; off > 0; off >>= 1) {
        curv += __shfl_down(curv, off);
        cnt  += __shfl_down(cnt,  off);
        dvel += __shfl_down(dvel, off);
        jerk += __shfl_down(jerk, off);
        ssum += __shfl_down(ssum, off);
        ssq  += __shfl_down(ssq,  off);
        fsum += __shfl_down(fsum, off);
        fsq  += __shfl_down(fsq,  off);
    }

    __shared__ float red[BLOCK / 64][8];
    const int lane = threadIdx.x & 63;
    const int wid  = threadIdx.x >> 6;
    if (lane == 0) {
        red[wid][0] = curv; red[wid][1] = cnt;
        red[wid][2] = dvel; red[wid][3] = jerk;
        red[wid][4] = ssum; red[wid][5] = ssq;
        red[wid][6] = fsum; red[wid][7] = fsq;
    }
    __syncthreads();

    if (threadIdx.x == 0) {
        float C = 0.f, N = 0.f, D = 0.f, J = 0.f, S = 0.f, S2 = 0.f, F = 0.f, F2 = 0.f;
#pragma unroll
        for (int w = 0; w < BLOCK / 64; ++w) {
            C  += red[w][0]; N  += red[w][1];
            D  += red[w][2]; J  += red[w][3];
            S  += red[w][4]; S2 += red[w][5];
            F  += red[w][6]; F2 += red[w][7];
        }
        const float inv_pairs = 1.f / (float)(2 * (TRAJ_LEN - 1));  // 2*2047 elements
        const float invT = 1.f / (float)TRAJ_LEN;

        float path_curvature = (N > 0.f) ? (C / N) : 0.f;
        float velocity_smoothness = 1.f / (1.f + D * inv_pairs);
        float acceleration_jerk = J * inv_pairs;

        float ms = S * invT;
        float vvar = S2 * invT - ms * ms;
        vvar = vvar > 0.f ? vvar : 0.f;
        float movement_rhythm = sqrtf(vvar) / (ms + 1e-6f);

        float mf = F * invT;
        float fvar = F2 * invT - mf * mf;
        fvar = fvar > 0.f ? fvar : 0.f;
        float force_modulation = sqrtf(fvar) / (mf + 1e-6f);

        float* o = out + (size_t)b * 5;
        o[0] = path_curvature;
        o[1] = velocity_smoothness;
        o[2] = acceleration_jerk;
        o[3] = movement_rhythm;
        o[4] = force_modulation;
    }
}

extern "C" void kernel_launch(void* const* d_in, const int* in_sizes, int n_in,
                              void* d_out, int out_size, void* d_ws, size_t ws_size,
                              hipStream_t stream) {
    const float* traj = (const float*)d_in[0];
    float* out = (float*)d_out;
    const int B = in_sizes[0] / (TRAJ_LEN * 6);   // 4096
    sig_kernel<<<dim3(B), dim3(BLOCK), 0, stream>>>(traj, out);
}

// Round 2
// 270.361 us; speedup vs baseline: 1.0123x; 1.0123x over previous
//
#include <hip/hip_runtime.h>

#define TRAJ_LEN 2048
#define BLOCK 256
#define ROW_FLOATS 6
#define TRAJ_FLOATS (TRAJ_LEN * ROW_FLOATS)   // 12288 floats = 48 KB

__global__ __launch_bounds__(BLOCK) void sig_kernel(const float* __restrict__ traj,
                                                    float* __restrict__ out) {
    const int b = blockIdx.x;
    const float* base = traj + (size_t)b * TRAJ_FLOATS;

    // ---- Phase 1: coalesced float4 staging of the whole trajectory into LDS ----
    __shared__ float s[TRAJ_FLOATS];
    {
        const float4* g4 = (const float4*)base;          // 201 MB input is 16B-aligned per traj (48 KB stride)
        float4* s4 = (float4*)s;
#pragma unroll
        for (int i = 0; i < TRAJ_FLOATS / 4 / BLOCK; ++i) {
            int idx = threadIdx.x + i * BLOCK;
            s4[idx] = g4[idx];
        }
    }
    __syncthreads();

    // ---- Phase 2: strided row reduction from LDS ----
    float curv = 0.f, cnt = 0.f;
    float dvel = 0.f, jerk = 0.f;
    float ssum = 0.f, ssq = 0.f;
    float fsum = 0.f, fsq = 0.f;

#pragma unroll
    for (int i = 0; i < TRAJ_LEN / BLOCK; ++i) {
        const int r = threadIdx.x + i * BLOCK;
        const float* row = s + r * ROW_FLOATS;
        float px = row[0], py = row[1];
        float vx = row[2], vy = row[3];
        float ax = row[4], ay = row[5];

        float sp = sqrtf(vx * vx + vy * vy);
        ssum += sp;  ssq += vx * vx + vy * vy;
        float fo = sqrtf(ax * ax + ay * ay);
        fsum += fo;  fsq += ax * ax + ay * ay;

        if (r >= 1) {
            const float* prow = row - ROW_FLOATS;
            dvel += fabsf(vx - prow[2]) + fabsf(vy - prow[3]);
            jerk += fabsf(ax - prow[4]) + fabsf(ay - prow[5]);
            if (r >= 2) {
                // cumsum telescopes: v1 = traj[r-1,:2], v2 = traj[r,:2]
                float ppx = prow[0], ppy = prow[1];
                float cross = ppx * py - ppy * px;
                float n = sqrtf(ppx * ppx + ppy * ppy) * sqrtf(px * px + py * py);
                if (n > 1e-6f) {
                    curv += fabsf(cross) / n;
                    cnt += 1.f;
                }
            }
        }
    }

    // ---- wave butterfly reduce (64 lanes) ----
#pragma unroll
    for (int off = 32; off > 0; off >>= 1) {
        curv += __shfl_down(curv, off);
        cnt  += __shfl_down(cnt,  off);
        dvel += __shfl_down(dvel, off);
        jerk += __shfl_down(jerk, off);
        ssum += __shfl_down(ssum, off);
        ssq  += __shfl_down(ssq,  off);
        fsum += __shfl_down(fsum, off);
        fsq  += __shfl_down(fsq,  off);
    }

    __shared__ float red[BLOCK / 64][8];
    const int lane = threadIdx.x & 63;
    const int wid  = threadIdx.x >> 6;
    if (lane == 0) {
        red[wid][0] = curv; red[wid][1] = cnt;
        red[wid][2] = dvel; red[wid][3] = jerk;
        red[wid][4] = ssum; red[wid][5] = ssq;
        red[wid][6] = fsum; red[wid][7] = fsq;
    }
    __syncthreads();

    if (threadIdx.x == 0) {
        float C = 0.f, N = 0.f, D = 0.f, J = 0.f, S = 0.f, S2 = 0.f, F = 0.f, F2 = 0.f;
#pragma unroll
        for (int w = 0; w < BLOCK / 64; ++w) {
            C  += red[w][0]; N  += red[w][1];
            D  += red[w][2]; J  += red[w][3];
            S  += red[w][4]; S2 += red[w][5];
            F  += red[w][6]; F2 += red[w][7];
        }
        const float inv_pairs = 1.f / (float)(2 * (TRAJ_LEN - 1));
        const float invT = 1.f / (float)TRAJ_LEN;

        float path_curvature = (N > 0.f) ? (C / N) : 0.f;
        float velocity_smoothness = 1.f / (1.f + D * inv_pairs);
        float acceleration_jerk = J * inv_pairs;

        float ms = S * invT;
        float vvar = S2 * invT - ms * ms;
        vvar = vvar > 0.f ? vvar : 0.f;
        float movement_rhythm = sqrtf(vvar) / (ms + 1e-6f);

        float mf = F * invT;
        float fvar = F2 * invT - mf * mf;
        fvar = fvar > 0.f ? fvar : 0.f;
        float force_modulation = sqrtf(fvar) / (mf + 1e-6f);

        float* o = out + (size_t)b * 5;
        o[0] = path_curvature;
        o[1] = velocity_smoothness;
        o[2] = acceleration_jerk;
        o[3] = movement_rhythm;
        o[4] = force_modulation;
    }
}

extern "C" void kernel_launch(void* const* d_in, const int* in_sizes, int n_in,
                              void* d_out, int out_size, void* d_ws, size_t ws_size,
                              hipStream_t stream) {
    const float* traj = (const float*)d_in[0];
    float* out = (float*)d_out;
    const int B = in_sizes[0] / TRAJ_FLOATS;   // 4096
    sig_kernel<<<dim3(B), dim3(BLOCK), 0, stream>>>(traj, out);
}